// Round 11
// baseline (552.463 us; speedup 1.0000x reference)
//
#include <hip/hip_runtime.h>
#include <math.h>

#define NN 50000
#define NE 800000
#define GG 64
#define SCAN_BLK 512
#define SCAN_NB ((NN + SCAN_BLK - 1) / SCAN_BLK)   // 98
#define CSR_CAP (NE + 4 * NN)                      // 4-aligned-per-node CSR capacity
#define NBLK ((NN + 63) / 64)                      // 782 proj blocks

typedef unsigned int uint;
typedef unsigned short ushort;
typedef __attribute__((ext_vector_type(8))) short short8v;  // 8 bf16 (4 VGPRs)
typedef __attribute__((ext_vector_type(4))) float f32x4;

__device__ __forceinline__ uint bf16r(float x) {   // RNE f32 -> bf16 bits
    uint u = __float_as_uint(x);
    return (u + 0x7fffu + ((u >> 16) & 1u)) >> 16;
}

// sum over each 8-lane group, broadcast to all 8 (pure DPP: xor1, xor2, half-mirror)
__device__ __forceinline__ float red8(float x) {
    float t;
    t = __int_as_float(__builtin_amdgcn_update_dpp(0, __float_as_int(x), 0xB1, 0xF, 0xF, 1));  // quad_perm [1,0,3,2]
    x += t;
    t = __int_as_float(__builtin_amdgcn_update_dpp(0, __float_as_int(x), 0x4E, 0xF, 0xF, 1));  // quad_perm [2,3,0,1]
    x += t;
    t = __int_as_float(__builtin_amdgcn_update_dpp(0, __float_as_int(x), 0x141, 0xF, 0xF, 1)); // row_half_mirror
    x += t;
    return x;
}

// ---------------- CSR build ----------------

__global__ __launch_bounds__(256) void k_degrank(const int* __restrict__ dstv,
                                                 int* __restrict__ deg,
                                                 int* __restrict__ rank) {
    int e = blockIdx.x * 256 + threadIdx.x;
    if (e < NE) rank[e] = atomicAdd(&deg[dstv[e]], 1);
}

__global__ __launch_bounds__(SCAN_BLK) void k_scan1(const int* __restrict__ deg,
                                                    int* __restrict__ locoff,
                                                    int* __restrict__ bsum) {
    __shared__ int sh[SCAN_BLK];
    int tid = threadIdx.x;
    int n = blockIdx.x * SCAN_BLK + tid;
    int v = (n < NN) ? ((deg[n] + 3) & ~3) : 0;
    sh[tid] = v;
    __syncthreads();
    for (int off = 1; off < SCAN_BLK; off <<= 1) {
        int t = (tid >= off) ? sh[tid - off] : 0;
        __syncthreads();
        sh[tid] += t;
        __syncthreads();
    }
    if (n < NN) locoff[n] = sh[tid] - v;   // exclusive
    if (tid == SCAN_BLK - 1) bsum[blockIdx.x] = sh[tid];
}

// scan2 over block sums + graph segment bounds (independent jobs, one launch)
__global__ void k_scan2b(int* __restrict__ bsum,
                         const int* __restrict__ batch,
                         int* __restrict__ bstart,
                         float* __restrict__ inv) {
    __shared__ int sh[128];
    __shared__ int sb[65];
    int t = threadIdx.x;
    int v = (t < SCAN_NB) ? bsum[t] : 0;
    sh[t] = v;
    __syncthreads();
    for (int off = 1; off < 128; off <<= 1) {
        int u = (t >= off) ? sh[t - off] : 0;
        __syncthreads();
        sh[t] += u;
        __syncthreads();
    }
    if (t < SCAN_NB) bsum[t] = sh[t] - v;  // exclusive
    if (t <= 64) {
        int lo = 0, hi = NN;
        while (lo < hi) { int mid = (lo + hi) >> 1; if (batch[mid] < t) lo = mid + 1; else hi = mid; }
        sb[t] = lo;
        bstart[t] = lo;
    }
    __syncthreads();
    if (t < 64) inv[t] = 1.0f / fmaxf((float)(sb[t + 1] - sb[t]), 1.0f);
}

// per-edge pass: ONLY the two small int scatters (no attr staging)
__global__ __launch_bounds__(256) void k_scatter(const int* __restrict__ srcv,
                                                 const int* __restrict__ dstv,
                                                 const int* __restrict__ locoff,
                                                 const int* __restrict__ bsum,
                                                 const int* __restrict__ rank,
                                                 int* __restrict__ srcp,
                                                 int* __restrict__ e2p) {
    int e = blockIdx.x * 256 + threadIdx.x;
    if (e >= NE) return;
    int d = dstv[e];
    int p = locoff[d] + bsum[d >> 9] + rank[e];
    srcp[p] = srcv[e] << 8;                 // 256 B per KVp row
    e2p[p] = e;
}

// per-slot pull-gather DIRECT from f32 eattr (L3-resident): convert + write
// aperm coalesced, pass-interleaved: slot s=p&3, uint t -> index 2t+(s&1)*16+(s>>1)
__global__ __launch_bounds__(256) void k_gather(const int* __restrict__ e2p,
                                                const float* __restrict__ eattr,
                                                uint* __restrict__ aperm32) {
    int p = blockIdx.x * 256 + threadIdx.x;
    if (p >= CSR_CAP) return;
    int e = e2p[p];
    const float4* ea = reinterpret_cast<const float4*>(eattr + (size_t)e * 16);
    float4 a = ea[0], b = ea[1], c = ea[2], d4 = ea[3];
    uint u0 = bf16r(a.x) | (bf16r(a.y) << 16);
    uint u1 = bf16r(a.z) | (bf16r(a.w) << 16);
    uint u2 = bf16r(b.x) | (bf16r(b.y) << 16);
    uint u3 = bf16r(b.z) | (bf16r(b.w) << 16);
    uint u4 = bf16r(c.x) | (bf16r(c.y) << 16);
    uint u5 = bf16r(c.z) | (bf16r(c.w) << 16);
    uint u6 = bf16r(d4.x) | (bf16r(d4.y) << 16);
    uint u7 = bf16r(d4.z) | (bf16r(d4.w) << 16);
    uint* base = aperm32 + (size_t)(p >> 2) * 32 + (p & 1) * 16 + ((p >> 1) & 1);
    base[0]  = u0;  base[2]  = u1;  base[4]  = u2;  base[6]  = u3;
    base[8]  = u4;  base[10] = u5;  base[12] = u6;  base[14] = u7;
}

// ---------------- pack combined weight matrix into MFMA B-fragment order ----------------

__global__ __launch_bounds__(256) void k_wfrag(const float* __restrict__ Wq,
                                               const float* __restrict__ Wk,
                                               const float* __restrict__ Wv,
                                               const float* __restrict__ Wsk,
                                               const float* __restrict__ We,
                                               ushort* __restrict__ Wf) {
    int t = blockIdx.x * 256 + threadIdx.x;
    if (t >= 5 * 20 * 2 * 64) return;
    int l = t / (20 * 2 * 64);
    int rem = t % (20 * 2 * 64);
    int nt = rem >> 7, s = (rem >> 6) & 1, lane = rem & 63;
    int c = nt * 16 + (lane & 15);
    int k0 = s * 32 + 8 * (lane >> 4);
    int msel = c >> 6, cc = c & 63;
    const float C2 = 0.36067376022224085f;
    ushort o[8];
    if (msel == 4) {
        int hh = cc >> 4, ja = cc & 15;
        const float* we = We + l * 1024 + ja * 64 + hh * 16;
#pragma unroll
        for (int j = 0; j < 8; ++j) {
            const float* wq = Wq + l * 4096 + (k0 + j) * 64 + hh * 16;
            float acc = 0.f;
#pragma unroll
            for (int dd = 0; dd < 16; ++dd) acc += wq[dd] * we[dd];
            o[j] = (ushort)bf16r(acc * C2);
        }
    } else {
        const float* W = (msel == 0) ? Wq + l * 4096 :
                         (msel == 1) ? Wk + l * 4096 :
                         (msel == 2) ? Wv + l * 4096 : Wsk + l * 4096;
        float sc = (msel == 0) ? C2 : 1.0f;
#pragma unroll
        for (int j = 0; j < 8; ++j) o[j] = (ushort)bf16r(W[(k0 + j) * 64 + cc] * sc);
    }
    uint4* dst = reinterpret_cast<uint4*>(Wf + (size_t)t * 8);
    uint4 u;
    u.x = (uint)o[0] | ((uint)o[1] << 16);
    u.y = (uint)o[2] | ((uint)o[3] << 16);
    u.z = (uint)o[4] | ((uint)o[5] << 16);
    u.w = (uint)o[6] | ((uint)o[7] << 16);
    dst[0] = u;
}

// ---------------- MFMA projection: [64 nodes] x [64] @ [64 x 320], LDS-free ----------------

template<bool L0>
__global__ __launch_bounds__(256) void k_projm(const float* __restrict__ x,
                                               const ushort* __restrict__ Hin,
                                               const ushort* __restrict__ Wfl,
                                               uint* __restrict__ QQp,
                                               uint* __restrict__ KVp,
                                               ushort* __restrict__ Sbh) {
    int tid = threadIdx.x, lane = tid & 63, wv = tid >> 6;
    int n0 = blockIdx.x * 64;
    int arow = lane & 15, agrp = lane >> 4;

    short8v A[4][2];
#pragma unroll
    for (int mt = 0; mt < 4; ++mt) {
        int node = n0 + mt * 16 + arow;
        if (node >= NN) node = NN - 1;        // clamped load; stores guarded below
#pragma unroll
        for (int s = 0; s < 2; ++s) {
            int k0 = s * 32 + agrp * 8;
            if (L0) {
                const float* hp = x + (size_t)node * 64 + k0;
                float4 u = *reinterpret_cast<const float4*>(hp);
                float4 v = *reinterpret_cast<const float4*>(hp + 4);
                short8v a;
                a[0] = (short)bf16r(u.x); a[1] = (short)bf16r(u.y);
                a[2] = (short)bf16r(u.z); a[3] = (short)bf16r(u.w);
                a[4] = (short)bf16r(v.x); a[5] = (short)bf16r(v.y);
                a[6] = (short)bf16r(v.z); a[7] = (short)bf16r(v.w);
                A[mt][s] = a;
            } else {
                A[mt][s] = *reinterpret_cast<const short8v*>(Hin + (size_t)node * 64 + k0);
            }
        }
    }

    int ch = wv * 16 + arow;
    int rb = agrp * 4;
    f32x4 qh[4], kh[4];
    const f32x4 z = {0.f, 0.f, 0.f, 0.f};

#pragma unroll
    for (int ni = 0; ni < 5; ++ni) {
        int ntl = wv + 4 * ni;   // col-tile: ni selects {Q,K,V,Sk,QW}, wv the 16-ch slice
        f32x4 acc[4] = {z, z, z, z};
#pragma unroll
        for (int s = 0; s < 2; ++s) {
            short8v B = *reinterpret_cast<const short8v*>(
                Wfl + (((size_t)ntl * 2 + s) * 64 + lane) * 8);
#pragma unroll
            for (int mt = 0; mt < 4; ++mt)
                acc[mt] = __builtin_amdgcn_mfma_f32_16x16x32_bf16(A[mt][s], B, acc[mt], 0, 0, 0);
        }
        if (ni == 0) {
#pragma unroll
            for (int mt = 0; mt < 4; ++mt) qh[mt] = acc[mt];
        } else if (ni == 1) {
#pragma unroll
            for (int mt = 0; mt < 4; ++mt) kh[mt] = acc[mt];
        } else if (ni == 2) {            // V ready: pack K|V
#pragma unroll
            for (int mt = 0; mt < 4; ++mt)
#pragma unroll
                for (int r = 0; r < 4; ++r) {
                    int node = n0 + mt * 16 + rb + r;
                    if (node < NN)
                        KVp[(size_t)node * 64 + ch] = (bf16r(kh[mt][r]) << 16) | bf16r(acc[mt][r]);
                }
        } else if (ni == 3) {            // skip projection, bf16
#pragma unroll
            for (int mt = 0; mt < 4; ++mt)
#pragma unroll
                for (int r = 0; r < 4; ++r) {
                    int node = n0 + mt * 16 + rb + r;
                    if (node < NN) Sbh[(size_t)node * 64 + ch] = (ushort)bf16r(acc[mt][r]);
                }
        } else {                          // QW ready: pack Q|QW
#pragma unroll
            for (int mt = 0; mt < 4; ++mt)
#pragma unroll
                for (int r = 0; r < 4; ++r) {
                    int node = n0 + mt * 16 + rb + r;
                    if (node < NN)
                        QQp[(size_t)node * 64 + ch] = (bf16r(qh[mt][r]) << 16) | bf16r(acc[mt][r]);
                }
        }
    }
}

// ---------------- attention: 2 edges/wave x 32 lanes x 2 channels/lane ----------------
// 3-deep superbatch pipeline (12 edges of gathers in flight), 8-lane DPP reduce,
// no max-tracking, scale pre-folded into weights, bf16 skip.

__global__ __launch_bounds__(256) void k_attn(const uint* __restrict__ QQp,
                                              const uint* __restrict__ KVp,
                                              const ushort* __restrict__ Sbh,
                                              const float* __restrict__ Wel,
                                              const uint* __restrict__ aperm32,
                                              const int* __restrict__ srcp,
                                              const int* __restrict__ locoff,
                                              const int* __restrict__ bsum,
                                              const int* __restrict__ cnt,
                                              ushort* __restrict__ Hout) {
    __shared__ float we[16 * 64];   // 4 KB, f32 [j][c]
    int tid = threadIdx.x;
    for (int i = tid; i < 1024; i += 256) we[i] = Wel[i];
    __syncthreads();

    int lane = tid & 63;
    int n = blockIdx.x * 4 + (tid >> 6);
    if (n >= NN) return;

    int pc = lane & 31;      // channel pair -> channels 2pc, 2pc+1
    int eh = lane >> 5;      // edge half
    int hd = pc >> 3;        // head

    uint2 qq = *reinterpret_cast<const uint2*>(QQp + n * 64 + 2 * pc);
    float qf0  = __uint_as_float(qq.x & 0xffff0000u);
    float qwf0 = __uint_as_float(qq.x << 16);
    float qf1  = __uint_as_float(qq.y & 0xffff0000u);
    float qwf1 = __uint_as_float(qq.y << 16);

    int dg = cnt[n];
    int pos0 = locoff[n] + bsum[n >> 9];
    int npass = (dg + 1) >> 1;
    int nsb = (npass + 1) >> 1;          // superbatch = 4 edges = 2 passes

    const char* kvb = (const char*)KVp + pc * 8;
    const uint2* apb2 = reinterpret_cast<const uint2*>(aperm32 + (size_t)pos0 * 8)
                        + (pc & 7) + eh * 8;

    float s = 0.f, av0 = 0.f, av1 = 0.f, aa0 = 0.f, aa1 = 0.f;

    auto ldidxg = [&](int j, int4& s4) {
        s4 = make_int4(0, 0, 0, 0);
        if (j < nsb) s4 = *reinterpret_cast<const int4*>(srcp + pos0 + j * 4);
    };
    auto issueg = [&](int j, const int4& s4, uint2 (&kv)[2], uint2& au) {
        if (j < nsb) {
            int sn0 = eh ? s4.y : s4.x;          // pass 0: slots j*4 + {0,1}
            int sn1 = eh ? s4.w : s4.z;          // pass 1: slots j*4 + {2,3}
            kv[0] = *reinterpret_cast<const uint2*>(kvb + sn0);
            kv[1] = *reinterpret_cast<const uint2*>(kvb + sn1);
            au = apb2[(size_t)j * 16];
        } else {
            kv[0] = make_uint2(0, 0);
            kv[1] = make_uint2(0, 0);
            au = make_uint2(0, 0);
        }
    };
    auto computeSB = [&](int j, const uint2 (&kv)[2], const uint2& au) {
#pragma unroll
        for (int p = 0; p < 2; ++p) {
            uint a_u = p ? au.y : au.x;
            float kf0 = __uint_as_float(kv[p].x & 0xffff0000u);
            float vf0 = __uint_as_float(kv[p].x << 16);
            float kf1 = __uint_as_float(kv[p].y & 0xffff0000u);
            float vf1 = __uint_as_float(kv[p].y << 16);
            float af0 = __uint_as_float(a_u << 16);
            float af1 = __uint_as_float(a_u & 0xffff0000u);
            float d = qf0 * kf0;
            d = fmaf(qf1, kf1, d);
            d = fmaf(qwf0, af0, d);
            d = fmaf(qwf1, af1, d);
            d = red8(d);
            int ei = j * 4 + p * 2 + eh;
            float l = (ei < dg) ? d : -1e30f;
            float a = __builtin_amdgcn_exp2f(l);
            s += a;
            av0 = fmaf(a, vf0, av0);
            av1 = fmaf(a, vf1, av1);
            aa0 = fmaf(a, af0, aa0);
            aa1 = fmaf(a, af1, aa1);
        }
    };

    // 3-deep pipeline: buffers A,B,C; index queue ia,ib,ic one iteration ahead
    int4 ia, ib, ic;
    uint2 kvA[2], kvB[2], kvC[2];
    uint2 auA, auB, auC;

    ldidxg(0, ia);
    ldidxg(1, ib);
    ldidxg(2, ic);
    issueg(0, ia, kvA, auA); ldidxg(3, ia);
    issueg(1, ib, kvB, auB); ldidxg(4, ib);
    issueg(2, ic, kvC, auC); ldidxg(5, ic);

    int nfull = nsb / 3;
    int jb = 0;
    for (int it = 0; it < nfull; ++it, jb += 3) {
        computeSB(jb, kvA, auA);
        issueg(jb + 3, ia, kvA, auA); ldidxg(jb + 6, ia);
        computeSB(jb + 1, kvB, auB);
        issueg(jb + 4, ib, kvB, auB); ldidxg(jb + 7, ib);
        computeSB(jb + 2, kvC, auC);
        issueg(jb + 5, ic, kvC, auC); ldidxg(jb + 8, ic);
    }
    int r = nsb - jb;
    if (r > 0) computeSB(jb, kvA, auA);
    if (r > 1) computeSB(jb + 1, kvB, auB);

    // merge the two edge-halves
    s   += __shfl_xor(s, 32);
    av0 += __shfl_xor(av0, 32);
    av1 += __shfl_xor(av1, 32);
    aa0 += __shfl_xor(aa0, 32);
    aa1 += __shfl_xor(aa1, 32);

    float rden = 1.0f / (s + 1e-16f);
    float e0 = 0.f, e1 = 0.f;
#pragma unroll
    for (int t = 0; t < 8; ++t) {
        float ae = __shfl(aa0, hd * 8 + t, 32);   // attr channel 2t
        float ao = __shfl(aa1, hd * 8 + t, 32);   // attr channel 2t+1
        float2 wE = *reinterpret_cast<const float2*>(&we[(2 * t) * 64 + 2 * pc]);
        float2 wO = *reinterpret_cast<const float2*>(&we[(2 * t + 1) * 64 + 2 * pc]);
        e0 = fmaf(ae, wE.x, fmaf(ao, wO.x, e0));
        e1 = fmaf(ae, wE.y, fmaf(ao, wO.y, e1));
    }
    uint sbu = *reinterpret_cast<const uint*>(Sbh + (size_t)n * 64 + 2 * pc);
    float sk0 = __uint_as_float(sbu << 16);
    float sk1 = __uint_as_float(sbu & 0xffff0000u);
    float hn0 = fmaxf(fmaf(av0 + e0, rden, sk0), 0.f);
    float hn1 = fmaxf(fmaf(av1 + e1, rden, sk1), 0.f);
    if (lane < 32) {
        uint hw = bf16r(hn0) | (bf16r(hn1) << 16);
        reinterpret_cast<uint*>(Hout)[(size_t)n * 32 + pc] = hw;
    }
}

// ---------------- mean pool ALL 5 layers at the end: 320 blocks (g,layer) ----------------

__global__ __launch_bounds__(512) void k_pool5(const ushort* __restrict__ Hb,
                                               const int* __restrict__ bstart,
                                               const float* __restrict__ inv,
                                               float* __restrict__ hcat) {
    __shared__ float red[512];
    int l = blockIdx.x >> 6, g = blockIdx.x & 63;
    int lo = bstart[g], hi = bstart[g + 1];
    const ushort* H = Hb + (size_t)l * NN * 64;
    int ch = threadIdx.x & 63, ro = threadIdx.x >> 6;   // 8 row stripes
    float acc = 0.f;
    for (int r = lo + ro; r < hi; r += 8)
        acc += __uint_as_float((uint)H[(size_t)r * 64 + ch] << 16);
    red[threadIdx.x] = acc;
    __syncthreads();
    if (ro < 4) red[threadIdx.x] += red[threadIdx.x + 256];
    __syncthreads();
    if (ro < 2) red[threadIdx.x] += red[threadIdx.x + 128];
    __syncthreads();
    if (ro == 0)
        hcat[g * 320 + l * 64 + ch] = (red[ch] + red[64 + ch]) * inv[g];
}

// ---------------- final MLP: one block per graph ----------------

__global__ __launch_bounds__(256) void k_mlp(const float* __restrict__ hcat,
                                             const float* __restrict__ W1,
                                             const float* __restrict__ b1,
                                             const float* __restrict__ W2,
                                             const float* __restrict__ b2,
                                             float* __restrict__ out) {
    __shared__ float hc[320];
    __shared__ float red[256];
    int g = blockIdx.x, tid = threadIdx.x;
    for (int i = tid; i < 320; i += 256) hc[i] = hcat[g * 320 + i];
    __syncthreads();
    float part = 0.f;
    for (int j = tid; j < 320; j += 256) {
        float t = b1[j];
        for (int k = 0; k < 320; ++k) t = fmaf(hc[k], W1[k * 320 + j], t);
        part = fmaf(fmaxf(t, 0.f), W2[j], part);
    }
    red[tid] = part;
    __syncthreads();
    for (int off = 128; off > 0; off >>= 1) {
        if (tid < off) red[tid] += red[tid + off];
        __syncthreads();
    }
    if (tid == 0) out[g] = red[0] + b2[0];
}

// ---------------- launch ----------------

extern "C" void kernel_launch(void* const* d_in, const int* in_sizes, int n_in,
                              void* d_out, int out_size, void* d_ws, size_t ws_size,
                              hipStream_t stream) {
    const float* x     = (const float*)d_in[0];
    const int*   ei    = (const int*)d_in[1];     // [2,E]: src then dst
    const float* eattr = (const float*)d_in[2];
    const int*   batch = (const int*)d_in[3];
    const float* Wq    = (const float*)d_in[4];
    const float* Wk    = (const float*)d_in[5];
    const float* Wv    = (const float*)d_in[6];
    const float* We    = (const float*)d_in[7];
    const float* Wsk   = (const float*)d_in[8];
    const float* W1    = (const float*)d_in[9];
    const float* b1    = (const float*)d_in[10];
    const float* W2    = (const float*)d_in[11];
    const float* b2    = (const float*)d_in[12];
    float* out = (float*)d_out;

    const int* srcv = ei;
    const int* dstv = ei + NE;

    // workspace carve (float words; all bases 16B-aligned)
    float* ws = (float*)d_ws;
    size_t o = 0;
    uint*   QQp = (uint*)(ws + o); o += (size_t)NN * 64;
    uint*   KVp = (uint*)(ws + o); o += (size_t)NN * 64;
    ushort* Sbh = (ushort*)(ws + o); o += (size_t)NN * 32;           // bf16 skip
    ushort* Hb  = (ushort*)(ws + o); o += (size_t)5 * NN * 64 / 2;   // 5 bf16 layer outputs
    ushort* Wf  = (ushort*)(ws + o); o += 5 * 20 * 2 * 64 * 8 / 2;   // frag-packed weights
    float*  inv = ws + o;          o += GG;
    float*  hcat = ws + o;         o += GG * 320;
    int*    bstart = (int*)(ws + o); o += 68;
    // ---- zeroed region start ----
    int*    deg  = (int*)(ws + o); o += NN;
    int*    srcp = (int*)(ws + o); o += CSR_CAP;   // pad slots must be 0 (safe gathers)
    int*    e2p  = (int*)(ws + o); o += CSR_CAP;   // pad slots -> edge 0 (finite attrs)
    size_t  zwords = (size_t)NN + 2 * (size_t)CSR_CAP;
    // ---- zeroed region end ----
    int*    rank   = (int*)(ws + o); o += NE;
    int*    locoff = (int*)(ws + o); o += NN;
    int*    bsum   = (int*)(ws + o); o += 128;
    ushort* aperm  = (ushort*)(ws + o); o += (size_t)CSR_CAP * 8;    // CSR-order, pass-interleaved

    hipMemsetAsync(deg, 0, zwords * 4, stream);

    k_degrank<<<(NE + 255) / 256, 256, 0, stream>>>(dstv, deg, rank);
    k_scan1<<<SCAN_NB, SCAN_BLK, 0, stream>>>(deg, locoff, bsum);
    k_scan2b<<<1, 128, 0, stream>>>(bsum, batch, bstart, inv);
    k_scatter<<<(NE + 255) / 256, 256, 0, stream>>>(srcv, dstv, locoff, bsum,
                                                    rank, srcp, e2p);
    k_gather<<<(CSR_CAP + 255) / 256, 256, 0, stream>>>(e2p, eattr, (uint*)aperm);
    k_wfrag<<<50, 256, 0, stream>>>(Wq, Wk, Wv, Wsk, We, Wf);

    for (int l = 0; l < 5; ++l) {
        const ushort* Wfl = Wf + (size_t)l * 20 * 2 * 64 * 8;
        if (l == 0)
            k_projm<true><<<NBLK, 256, 0, stream>>>(x, Hb, Wfl, QQp, KVp, Sbh);
        else
            k_projm<false><<<NBLK, 256, 0, stream>>>(x, Hb + (size_t)(l - 1) * NN * 64,
                                                     Wfl, QQp, KVp, Sbh);
        k_attn<<<(NN + 3) / 4, 256, 0, stream>>>(QQp, KVp, Sbh,
                                                 We + l * 1024,
                                                 (const uint*)aperm,
                                                 srcp, locoff, bsum, deg,
                                                 Hb + (size_t)l * NN * 64);
    }
    k_pool5<<<320, 512, 0, stream>>>(Hb, bstart, inv, hcat);
    k_mlp<<<GG, 256, 0, stream>>>(hcat, W1, b1, W2, b2, out);
}

// Round 12
// 469.972 us; speedup vs baseline: 1.1755x; 1.1755x over previous
//
#include <hip/hip_runtime.h>
#include <math.h>

#define NN 50000
#define NE 800000
#define GG 64
#define SCAN_BLK 512
#define SCAN_NB ((NN + SCAN_BLK - 1) / SCAN_BLK)   // 98
#define CSR_CAP (NE + 4 * NN)                      // 4-aligned-per-node CSR capacity
#define NBLK ((NN + 63) / 64)                      // 782 proj blocks

typedef unsigned int uint;
typedef unsigned short ushort;
typedef __attribute__((ext_vector_type(8))) short short8v;  // 8 bf16 (4 VGPRs)
typedef __attribute__((ext_vector_type(4))) float f32x4;

__device__ __forceinline__ uint bf16r(float x) {   // RNE f32 -> bf16 bits
    uint u = __float_as_uint(x);
    return (u + 0x7fffu + ((u >> 16) & 1u)) >> 16;
}

// sum over each 8-lane group, broadcast to all 8 (pure DPP: xor1, xor2, half-mirror)
__device__ __forceinline__ float red8(float x) {
    float t;
    t = __int_as_float(__builtin_amdgcn_update_dpp(0, __float_as_int(x), 0xB1, 0xF, 0xF, 1));  // quad_perm [1,0,3,2]
    x += t;
    t = __int_as_float(__builtin_amdgcn_update_dpp(0, __float_as_int(x), 0x4E, 0xF, 0xF, 1));  // quad_perm [2,3,0,1]
    x += t;
    t = __int_as_float(__builtin_amdgcn_update_dpp(0, __float_as_int(x), 0x141, 0xF, 0xF, 1)); // row_half_mirror
    x += t;
    return x;
}

// ---------------- CSR build ----------------

__global__ __launch_bounds__(256) void k_degrank(const int* __restrict__ dstv,
                                                 int* __restrict__ deg,
                                                 int* __restrict__ rank) {
    int e = blockIdx.x * 256 + threadIdx.x;
    if (e < NE) rank[e] = atomicAdd(&deg[dstv[e]], 1);
}

__global__ __launch_bounds__(SCAN_BLK) void k_scan1(const int* __restrict__ deg,
                                                    int* __restrict__ locoff,
                                                    int* __restrict__ bsum) {
    __shared__ int sh[SCAN_BLK];
    int tid = threadIdx.x;
    int n = blockIdx.x * SCAN_BLK + tid;
    int v = (n < NN) ? ((deg[n] + 3) & ~3) : 0;
    sh[tid] = v;
    __syncthreads();
    for (int off = 1; off < SCAN_BLK; off <<= 1) {
        int t = (tid >= off) ? sh[tid - off] : 0;
        __syncthreads();
        sh[tid] += t;
        __syncthreads();
    }
    if (n < NN) locoff[n] = sh[tid] - v;   // exclusive
    if (tid == SCAN_BLK - 1) bsum[blockIdx.x] = sh[tid];
}

// scan2 over block sums + total used slots + graph segment bounds (one launch)
__global__ void k_scan2b(int* __restrict__ bsum,
                         const int* __restrict__ batch,
                         int* __restrict__ bstart,
                         float* __restrict__ inv,
                         int* __restrict__ ntot) {
    __shared__ int sh[128];
    __shared__ int sb[65];
    int t = threadIdx.x;
    int v = (t < SCAN_NB) ? bsum[t] : 0;
    sh[t] = v;
    __syncthreads();
    for (int off = 1; off < 128; off <<= 1) {
        int u = (t >= off) ? sh[t - off] : 0;
        __syncthreads();
        sh[t] += u;
        __syncthreads();
    }
    if (t < SCAN_NB) bsum[t] = sh[t] - v;  // exclusive
    if (t == 127) ntot[0] = sh[127];       // total used CSR slots
    if (t <= 64) {
        int lo = 0, hi = NN;
        while (lo < hi) { int mid = (lo + hi) >> 1; if (batch[mid] < t) lo = mid + 1; else hi = mid; }
        sb[t] = lo;
        bstart[t] = lo;
    }
    __syncthreads();
    if (t < 64) inv[t] = 1.0f / fmaxf((float)(sb[t + 1] - sb[t]), 1.0f);
}

// per-edge int scatters + per-node pad zeroing (tail threads)
__global__ __launch_bounds__(256) void k_scatter(const int* __restrict__ srcv,
                                                 const int* __restrict__ dstv,
                                                 const int* __restrict__ locoff,
                                                 const int* __restrict__ bsum,
                                                 const int* __restrict__ rank,
                                                 const int* __restrict__ deg,
                                                 int* __restrict__ srcp,
                                                 int* __restrict__ e2p) {
    int idx = blockIdx.x * 256 + threadIdx.x;
    if (idx < NE) {
        int d = dstv[idx];
        int p = locoff[d] + bsum[d >> 9] + rank[idx];
        srcp[p] = srcv[idx] << 8;           // 256 B per KVp row
        e2p[p] = idx;
    } else if (idx < NE + NN) {
        int nd = idx - NE;
        int start = locoff[nd] + bsum[nd >> 9];
        int dgn = deg[nd];
        int al = (dgn + 3) & ~3;
        for (int p = start + dgn; p < start + al; ++p) {
            srcp[p] = 0;
            e2p[p] = 0;
        }
    }
}

// per-slot pull-gather DIRECT from f32 eattr, bounded by device total; coalesced
// aperm writes, pass-interleaved: slot s=p&3, uint t -> index 2t+(s&1)*16+(s>>1)
__global__ __launch_bounds__(256) void k_gather(const int* __restrict__ e2p,
                                                const float* __restrict__ eattr,
                                                uint* __restrict__ aperm32,
                                                const int* __restrict__ ntot) {
    int tot = ntot[0];
    for (int p = blockIdx.x * 256 + threadIdx.x; p < tot; p += gridDim.x * 256) {
        int e = e2p[p];
        const float4* ea = reinterpret_cast<const float4*>(eattr + (size_t)e * 16);
        float4 a = ea[0], b = ea[1], c = ea[2], d4 = ea[3];
        uint u0 = bf16r(a.x) | (bf16r(a.y) << 16);
        uint u1 = bf16r(a.z) | (bf16r(a.w) << 16);
        uint u2 = bf16r(b.x) | (bf16r(b.y) << 16);
        uint u3 = bf16r(b.z) | (bf16r(b.w) << 16);
        uint u4 = bf16r(c.x) | (bf16r(c.y) << 16);
        uint u5 = bf16r(c.z) | (bf16r(c.w) << 16);
        uint u6 = bf16r(d4.x) | (bf16r(d4.y) << 16);
        uint u7 = bf16r(d4.z) | (bf16r(d4.w) << 16);
        uint* base = aperm32 + (size_t)(p >> 2) * 32 + (p & 1) * 16 + ((p >> 1) & 1);
        base[0]  = u0;  base[2]  = u1;  base[4]  = u2;  base[6]  = u3;
        base[8]  = u4;  base[10] = u5;  base[12] = u6;  base[14] = u7;
    }
}

// ---------------- pack combined weight matrix into MFMA B-fragment order ----------------

__global__ __launch_bounds__(256) void k_wfrag(const float* __restrict__ Wq,
                                               const float* __restrict__ Wk,
                                               const float* __restrict__ Wv,
                                               const float* __restrict__ Wsk,
                                               const float* __restrict__ We,
                                               ushort* __restrict__ Wf) {
    int t = blockIdx.x * 256 + threadIdx.x;
    if (t >= 5 * 20 * 2 * 64) return;
    int l = t / (20 * 2 * 64);
    int rem = t % (20 * 2 * 64);
    int nt = rem >> 7, s = (rem >> 6) & 1, lane = rem & 63;
    int c = nt * 16 + (lane & 15);
    int k0 = s * 32 + 8 * (lane >> 4);
    int msel = c >> 6, cc = c & 63;
    const float C2 = 0.36067376022224085f;
    ushort o[8];
    if (msel == 4) {
        int hh = cc >> 4, ja = cc & 15;
        const float* we = We + l * 1024 + ja * 64 + hh * 16;
#pragma unroll
        for (int j = 0; j < 8; ++j) {
            const float* wq = Wq + l * 4096 + (k0 + j) * 64 + hh * 16;
            float acc = 0.f;
#pragma unroll
            for (int dd = 0; dd < 16; ++dd) acc += wq[dd] * we[dd];
            o[j] = (ushort)bf16r(acc * C2);
        }
    } else {
        const float* W = (msel == 0) ? Wq + l * 4096 :
                         (msel == 1) ? Wk + l * 4096 :
                         (msel == 2) ? Wv + l * 4096 : Wsk + l * 4096;
        float sc = (msel == 0) ? C2 : 1.0f;
#pragma unroll
        for (int j = 0; j < 8; ++j) o[j] = (ushort)bf16r(W[(k0 + j) * 64 + cc] * sc);
    }
    uint4* dst = reinterpret_cast<uint4*>(Wf + (size_t)t * 8);
    uint4 u;
    u.x = (uint)o[0] | ((uint)o[1] << 16);
    u.y = (uint)o[2] | ((uint)o[3] << 16);
    u.z = (uint)o[4] | ((uint)o[5] << 16);
    u.w = (uint)o[6] | ((uint)o[7] << 16);
    dst[0] = u;
}

// ---------------- MFMA projection: [64 nodes] x [64] @ [64 x 320], LDS-free ----------------

template<bool L0>
__global__ __launch_bounds__(256) void k_projm(const float* __restrict__ x,
                                               const ushort* __restrict__ Hin,
                                               const ushort* __restrict__ Wfl,
                                               uint* __restrict__ QQp,
                                               uint* __restrict__ KVp,
                                               ushort* __restrict__ Sbh) {
    int tid = threadIdx.x, lane = tid & 63, wv = tid >> 6;
    int n0 = blockIdx.x * 64;
    int arow = lane & 15, agrp = lane >> 4;

    short8v A[4][2];
#pragma unroll
    for (int mt = 0; mt < 4; ++mt) {
        int node = n0 + mt * 16 + arow;
        if (node >= NN) node = NN - 1;        // clamped load; stores guarded below
#pragma unroll
        for (int s = 0; s < 2; ++s) {
            int k0 = s * 32 + agrp * 8;
            if (L0) {
                const float* hp = x + (size_t)node * 64 + k0;
                float4 u = *reinterpret_cast<const float4*>(hp);
                float4 v = *reinterpret_cast<const float4*>(hp + 4);
                short8v a;
                a[0] = (short)bf16r(u.x); a[1] = (short)bf16r(u.y);
                a[2] = (short)bf16r(u.z); a[3] = (short)bf16r(u.w);
                a[4] = (short)bf16r(v.x); a[5] = (short)bf16r(v.y);
                a[6] = (short)bf16r(v.z); a[7] = (short)bf16r(v.w);
                A[mt][s] = a;
            } else {
                A[mt][s] = *reinterpret_cast<const short8v*>(Hin + (size_t)node * 64 + k0);
            }
        }
    }

    int ch = wv * 16 + arow;
    int rb = agrp * 4;
    f32x4 qh[4], kh[4];
    const f32x4 z = {0.f, 0.f, 0.f, 0.f};

#pragma unroll
    for (int ni = 0; ni < 5; ++ni) {
        int ntl = wv + 4 * ni;   // col-tile: ni selects {Q,K,V,Sk,QW}, wv the 16-ch slice
        f32x4 acc[4] = {z, z, z, z};
#pragma unroll
        for (int s = 0; s < 2; ++s) {
            short8v B = *reinterpret_cast<const short8v*>(
                Wfl + (((size_t)ntl * 2 + s) * 64 + lane) * 8);
#pragma unroll
            for (int mt = 0; mt < 4; ++mt)
                acc[mt] = __builtin_amdgcn_mfma_f32_16x16x32_bf16(A[mt][s], B, acc[mt], 0, 0, 0);
        }
        if (ni == 0) {
#pragma unroll
            for (int mt = 0; mt < 4; ++mt) qh[mt] = acc[mt];
        } else if (ni == 1) {
#pragma unroll
            for (int mt = 0; mt < 4; ++mt) kh[mt] = acc[mt];
        } else if (ni == 2) {            // V ready: pack K|V
#pragma unroll
            for (int mt = 0; mt < 4; ++mt)
#pragma unroll
                for (int r = 0; r < 4; ++r) {
                    int node = n0 + mt * 16 + rb + r;
                    if (node < NN)
                        KVp[(size_t)node * 64 + ch] = (bf16r(kh[mt][r]) << 16) | bf16r(acc[mt][r]);
                }
        } else if (ni == 3) {            // skip projection, bf16
#pragma unroll
            for (int mt = 0; mt < 4; ++mt)
#pragma unroll
                for (int r = 0; r < 4; ++r) {
                    int node = n0 + mt * 16 + rb + r;
                    if (node < NN) Sbh[(size_t)node * 64 + ch] = (ushort)bf16r(acc[mt][r]);
                }
        } else {                          // QW ready: pack Q|QW
#pragma unroll
            for (int mt = 0; mt < 4; ++mt)
#pragma unroll
                for (int r = 0; r < 4; ++r) {
                    int node = n0 + mt * 16 + rb + r;
                    if (node < NN)
                        QQp[(size_t)node * 64 + ch] = (bf16r(qh[mt][r]) << 16) | bf16r(acc[mt][r]);
                }
        }
    }
}

// ---------------- attention: 2 edges/wave x 32 lanes x 2 channels/lane ----------------
// 2-deep superbatch pipeline (round-10 structure), 8-lane DPP reduce,
// no max-tracking, scale pre-folded into weights, bf16 skip.

__global__ __launch_bounds__(256) void k_attn(const uint* __restrict__ QQp,
                                              const uint* __restrict__ KVp,
                                              const ushort* __restrict__ Sbh,
                                              const float* __restrict__ Wel,
                                              const uint* __restrict__ aperm32,
                                              const int* __restrict__ srcp,
                                              const int* __restrict__ locoff,
                                              const int* __restrict__ bsum,
                                              const int* __restrict__ cnt,
                                              ushort* __restrict__ Hout) {
    __shared__ float we[16 * 64];   // 4 KB, f32 [j][c]
    int tid = threadIdx.x;
    for (int i = tid; i < 1024; i += 256) we[i] = Wel[i];
    __syncthreads();

    int lane = tid & 63;
    int n = blockIdx.x * 4 + (tid >> 6);
    if (n >= NN) return;

    int pc = lane & 31;      // channel pair -> channels 2pc, 2pc+1
    int eh = lane >> 5;      // edge half
    int hd = pc >> 3;        // head

    uint2 qq = *reinterpret_cast<const uint2*>(QQp + n * 64 + 2 * pc);
    float qf0  = __uint_as_float(qq.x & 0xffff0000u);
    float qwf0 = __uint_as_float(qq.x << 16);
    float qf1  = __uint_as_float(qq.y & 0xffff0000u);
    float qwf1 = __uint_as_float(qq.y << 16);

    int dg = cnt[n];
    int pos0 = locoff[n] + bsum[n >> 9];
    int npass = (dg + 1) >> 1;
    int nsb = (npass + 1) >> 1;          // superbatch = 4 edges = 2 passes

    const char* kvb = (const char*)KVp + pc * 8;
    const uint2* apb2 = reinterpret_cast<const uint2*>(aperm32 + (size_t)pos0 * 8)
                        + (pc & 7) + eh * 8;

    float s = 0.f, av0 = 0.f, av1 = 0.f, aa0 = 0.f, aa1 = 0.f;

    auto ldidx = [&](int j, int4& s4) {
        s4 = (j < nsb) ? *reinterpret_cast<const int4*>(srcp + pos0 + j * 4)
                       : make_int4(0, 0, 0, 0);
    };
    auto issueSB = [&](int j, const int4& s4, uint2 (&kv)[2], uint2& au) {
        int sn0 = eh ? s4.y : s4.x;          // pass 0: slots j*4 + {0,1}
        int sn1 = eh ? s4.w : s4.z;          // pass 1: slots j*4 + {2,3}
        kv[0] = *reinterpret_cast<const uint2*>(kvb + sn0);
        kv[1] = *reinterpret_cast<const uint2*>(kvb + sn1);
        au = apb2[(size_t)j * 16];
    };
    auto computeSB = [&](int j, const uint2 (&kv)[2], const uint2& au) {
#pragma unroll
        for (int p = 0; p < 2; ++p) {
            uint a_u = p ? au.y : au.x;
            float kf0 = __uint_as_float(kv[p].x & 0xffff0000u);
            float vf0 = __uint_as_float(kv[p].x << 16);
            float kf1 = __uint_as_float(kv[p].y & 0xffff0000u);
            float vf1 = __uint_as_float(kv[p].y << 16);
            float af0 = __uint_as_float(a_u << 16);
            float af1 = __uint_as_float(a_u & 0xffff0000u);
            float d = qf0 * kf0;
            d = fmaf(qf1, kf1, d);
            d = fmaf(qwf0, af0, d);
            d = fmaf(qwf1, af1, d);
            d = red8(d);
            int ei = j * 4 + p * 2 + eh;
            float l = (ei < dg) ? d : -1e30f;
            float a = __builtin_amdgcn_exp2f(l);
            s += a;
            av0 = fmaf(a, vf0, av0);
            av1 = fmaf(a, vf1, av1);
            aa0 = fmaf(a, af0, aa0);
            aa1 = fmaf(a, af1, aa1);
        }
    };

    int4 s4a, s4b;
    uint2 kvA[2], kvB[2];
    uint2 auA, auB;

    ldidx(0, s4a);
    issueSB(0, s4a, kvA, auA);
    ldidx(1, s4b);

    int sb = 0;
    while (sb + 1 < nsb) {
        issueSB(sb + 1, s4b, kvB, auB);
        ldidx(sb + 2, s4a);
        computeSB(sb, kvA, auA);
        if (sb + 2 < nsb) {
            issueSB(sb + 2, s4a, kvA, auA);
            ldidx(sb + 3, s4b);
        }
        computeSB(sb + 1, kvB, auB);
        sb += 2;
    }
    if (sb < nsb) computeSB(sb, kvA, auA);

    // merge the two edge-halves
    s   += __shfl_xor(s, 32);
    av0 += __shfl_xor(av0, 32);
    av1 += __shfl_xor(av1, 32);
    aa0 += __shfl_xor(aa0, 32);
    aa1 += __shfl_xor(aa1, 32);

    float rden = 1.0f / (s + 1e-16f);
    float e0 = 0.f, e1 = 0.f;
#pragma unroll
    for (int t = 0; t < 8; ++t) {
        float ae = __shfl(aa0, hd * 8 + t, 32);   // attr channel 2t
        float ao = __shfl(aa1, hd * 8 + t, 32);   // attr channel 2t+1
        float2 wE = *reinterpret_cast<const float2*>(&we[(2 * t) * 64 + 2 * pc]);
        float2 wO = *reinterpret_cast<const float2*>(&we[(2 * t + 1) * 64 + 2 * pc]);
        e0 = fmaf(ae, wE.x, fmaf(ao, wO.x, e0));
        e1 = fmaf(ae, wE.y, fmaf(ao, wO.y, e1));
    }
    uint sbu = *reinterpret_cast<const uint*>(Sbh + (size_t)n * 64 + 2 * pc);
    float sk0 = __uint_as_float(sbu << 16);
    float sk1 = __uint_as_float(sbu & 0xffff0000u);
    float hn0 = fmaxf(fmaf(av0 + e0, rden, sk0), 0.f);
    float hn1 = fmaxf(fmaf(av1 + e1, rden, sk1), 0.f);
    if (lane < 32) {
        uint hw = bf16r(hn0) | (bf16r(hn1) << 16);
        reinterpret_cast<uint*>(Hout)[(size_t)n * 32 + pc] = hw;
    }
}

// ---------------- mean pool ALL 5 layers at the end: 320 blocks (g,layer) ----------------

__global__ __launch_bounds__(512) void k_pool5(const ushort* __restrict__ Hb,
                                               const int* __restrict__ bstart,
                                               const float* __restrict__ inv,
                                               float* __restrict__ hcat) {
    __shared__ float red[512];
    int l = blockIdx.x >> 6, g = blockIdx.x & 63;
    int lo = bstart[g], hi = bstart[g + 1];
    const ushort* H = Hb + (size_t)l * NN * 64;
    int ch = threadIdx.x & 63, ro = threadIdx.x >> 6;   // 8 row stripes
    float acc = 0.f;
    for (int r = lo + ro; r < hi; r += 8)
        acc += __uint_as_float((uint)H[(size_t)r * 64 + ch] << 16);
    red[threadIdx.x] = acc;
    __syncthreads();
    if (ro < 4) red[threadIdx.x] += red[threadIdx.x + 256];
    __syncthreads();
    if (ro < 2) red[threadIdx.x] += red[threadIdx.x + 128];
    __syncthreads();
    if (ro == 0)
        hcat[g * 320 + l * 64 + ch] = (red[ch] + red[64 + ch]) * inv[g];
}

// ---------------- final MLP: one block per graph ----------------

__global__ __launch_bounds__(256) void k_mlp(const float* __restrict__ hcat,
                                             const float* __restrict__ W1,
                                             const float* __restrict__ b1,
                                             const float* __restrict__ W2,
                                             const float* __restrict__ b2,
                                             float* __restrict__ out) {
    __shared__ float hc[320];
    __shared__ float red[256];
    int g = blockIdx.x, tid = threadIdx.x;
    for (int i = tid; i < 320; i += 256) hc[i] = hcat[g * 320 + i];
    __syncthreads();
    float part = 0.f;
    for (int j = tid; j < 320; j += 256) {
        float t = b1[j];
        for (int k = 0; k < 320; ++k) t = fmaf(hc[k], W1[k * 320 + j], t);
        part = fmaf(fmaxf(t, 0.f), W2[j], part);
    }
    red[tid] = part;
    __syncthreads();
    for (int off = 128; off > 0; off >>= 1) {
        if (tid < off) red[tid] += red[tid + off];
        __syncthreads();
    }
    if (tid == 0) out[g] = red[0] + b2[0];
}

// ---------------- launch ----------------

extern "C" void kernel_launch(void* const* d_in, const int* in_sizes, int n_in,
                              void* d_out, int out_size, void* d_ws, size_t ws_size,
                              hipStream_t stream) {
    const float* x     = (const float*)d_in[0];
    const int*   ei    = (const int*)d_in[1];     // [2,E]: src then dst
    const float* eattr = (const float*)d_in[2];
    const int*   batch = (const int*)d_in[3];
    const float* Wq    = (const float*)d_in[4];
    const float* Wk    = (const float*)d_in[5];
    const float* Wv    = (const float*)d_in[6];
    const float* We    = (const float*)d_in[7];
    const float* Wsk   = (const float*)d_in[8];
    const float* W1    = (const float*)d_in[9];
    const float* b1    = (const float*)d_in[10];
    const float* W2    = (const float*)d_in[11];
    const float* b2    = (const float*)d_in[12];
    float* out = (float*)d_out;

    const int* srcv = ei;
    const int* dstv = ei + NE;

    // workspace carve (float words; all bases 16B-aligned)
    float* ws = (float*)d_ws;
    size_t o = 0;
    uint*   QQp = (uint*)(ws + o); o += (size_t)NN * 64;
    uint*   KVp = (uint*)(ws + o); o += (size_t)NN * 64;
    ushort* Sbh = (ushort*)(ws + o); o += (size_t)NN * 32;           // bf16 skip
    ushort* Hb  = (ushort*)(ws + o); o += (size_t)5 * NN * 64 / 2;   // 5 bf16 layer outputs
    ushort* Wf  = (ushort*)(ws + o); o += 5 * 20 * 2 * 64 * 8 / 2;   // frag-packed weights
    float*  inv = ws + o;          o += GG;
    float*  hcat = ws + o;         o += GG * 320;
    int*    bstart = (int*)(ws + o); o += 68;
    int*    ntot   = (int*)(ws + o); o += 4;
    int*    deg  = (int*)(ws + o); o += NN;        // zeroed (only this)
    int*    srcp = (int*)(ws + o); o += CSR_CAP;   // pads zeroed by k_scatter tail
    int*    e2p  = (int*)(ws + o); o += CSR_CAP;   // pads zeroed by k_scatter tail
    int*    rank   = (int*)(ws + o); o += NE;
    int*    locoff = (int*)(ws + o); o += NN;
    int*    bsum   = (int*)(ws + o); o += 128;
    ushort* aperm  = (ushort*)(ws + o); o += (size_t)CSR_CAP * 8;    // CSR-order, pass-interleaved

    hipMemsetAsync(deg, 0, (size_t)NN * 4, stream);

    k_degrank<<<(NE + 255) / 256, 256, 0, stream>>>(dstv, deg, rank);
    k_scan1<<<SCAN_NB, SCAN_BLK, 0, stream>>>(deg, locoff, bsum);
    k_scan2b<<<1, 128, 0, stream>>>(bsum, batch, bstart, inv, ntot);
    k_scatter<<<(NE + NN + 255) / 256, 256, 0, stream>>>(srcv, dstv, locoff, bsum,
                                                         rank, deg, srcp, e2p);
    k_gather<<<4096, 256, 0, stream>>>(e2p, eattr, (uint*)aperm, ntot);
    k_wfrag<<<50, 256, 0, stream>>>(Wq, Wk, Wv, Wsk, We, Wf);

    for (int l = 0; l < 5; ++l) {
        const ushort* Wfl = Wf + (size_t)l * 20 * 2 * 64 * 8;
        if (l == 0)
            k_projm<true><<<NBLK, 256, 0, stream>>>(x, Hb, Wfl, QQp, KVp, Sbh);
        else
            k_projm<false><<<NBLK, 256, 0, stream>>>(x, Hb + (size_t)(l - 1) * NN * 64,
                                                     Wfl, QQp, KVp, Sbh);
        k_attn<<<(NN + 3) / 4, 256, 0, stream>>>(QQp, KVp, Sbh,
                                                 We + l * 1024,
                                                 (const uint*)aperm,
                                                 srcp, locoff, bsum, deg,
                                                 Hb + (size_t)l * NN * 64);
    }
    k_pool5<<<320, 512, 0, stream>>>(Hb, bstart, inv, hcat);
    k_mlp<<<GG, 256, 0, stream>>>(hcat, W1, b1, W2, b2, out);
}